// Round 1
// 646.551 us; speedup vs baseline: 1.0107x; 1.0107x over previous
//
#include <hip/hip_runtime.h>
#include <hip/hip_bf16.h>

// GWNN layer: out = (wavelets * filt[None,:]) @ (wavelets_inv @ (features @ W))
// ALL INPUTS/OUTPUT ARE FP32 in global memory (per reference dtypes).
// Internally: convert the big operands to bf16 and use MFMA; tolerance
// (9.56e-2, floor_eps_k=8) comfortably covers bf16 rounding (~0.03).
//
// Identity: (Wav * filt_cols) @ S == Wav @ (filt_rows * S) -- scale the small
// [8192,64] spectral matrix, never touch the 256 MB wavelet matrices.
//
// Both big GEMMs are [8192,8192]@[8192,64]: memory-bound on the fp32 A read
// (32 FLOP/byte, HBM floor ~43 us each). v2: double-buffered LDS + software
// pipeline (T3 2-phase / T14 issue-early-write-late) -- next tile's A loads
// and B global_load_lds are issued BEFORE the current tile's MFMA phase, so
// HBM latency hides under compute and ONE barrier/iter replaces two.

typedef unsigned short u16;
typedef short s16x8 __attribute__((ext_vector_type(8)));
typedef float f32x4 __attribute__((ext_vector_type(4)));

__device__ __forceinline__ u16 f2bf(float f) {
    unsigned u;
    __builtin_memcpy(&u, &f, 4);
    unsigned r = (u + 0x7fffu + ((u >> 16) & 1u)) >> 16;  // round-nearest-even
    return (u16)r;
}
__device__ __forceinline__ unsigned pk2(float a, float b) {
    // two fp32 -> packed bf16x2 (RNE), lowers to v_cvt_pk_bf16_f32 on gfx950
    __hip_bfloat162 h = __float22bfloat162_rn(float2{a, b});
    unsigned u;
    __builtin_memcpy(&u, &h, 4);
    return u;
}

#define GAS(p) ((const __attribute__((address_space(1))) void*)(p))
#define LAS(p) ((__attribute__((address_space(3))) void*)(p))

#define NN 8192
#define MT 64   // rows per block
#define BK 64   // k per staging iter

// ---------------------------------------------------------------------------
// k1: Tmp[8192][64] = features[8192][128] @ W[128][64]  (fp32 VALU, tiny)
__global__ __launch_bounds__(256) void k1_feat(const float* __restrict__ F,
                                               const float* __restrict__ W,
                                               float* __restrict__ Tmp) {
    const int tid = threadIdx.x;
    const int col = tid & 63;
    const int rq = tid >> 6;
    const int row0 = blockIdx.x * 16 + rq * 4;
    float a0 = 0.f, a1 = 0.f, a2 = 0.f, a3 = 0.f;
    const float* f0 = F + (size_t)row0 * 128;
    for (int k = 0; k < 128; k += 4) {
        f32x4 v0 = *(const f32x4*)(f0 + k);
        f32x4 v1 = *(const f32x4*)(f0 + 128 + k);
        f32x4 v2 = *(const f32x4*)(f0 + 256 + k);
        f32x4 v3 = *(const f32x4*)(f0 + 384 + k);
#pragma unroll
        for (int kk = 0; kk < 4; ++kk) {
            float wv = W[(k + kk) * 64 + col];
            a0 += v0[kk] * wv;
            a1 += v1[kk] * wv;
            a2 += v2[kk] * wv;
            a3 += v3[kk] * wv;
        }
    }
    Tmp[(size_t)(row0 + 0) * 64 + col] = a0;
    Tmp[(size_t)(row0 + 1) * 64 + col] = a1;
    Tmp[(size_t)(row0 + 2) * 64 + col] = a2;
    Tmp[(size_t)(row0 + 3) * 64 + col] = a3;
}

// ---------------------------------------------------------------------------
// k2: Tt[64][8192] (bf16) = transpose(Tmp[8192][64] fp32)
__global__ __launch_bounds__(256) void k2_transpose(const float* __restrict__ Tmp,
                                                    u16* __restrict__ Tt) {
    __shared__ u16 s[64][65];
    const int tid = threadIdx.x;
    const int r0 = blockIdx.x * 64;
    const int c = tid & 63, r = tid >> 6;
#pragma unroll
    for (int p = 0; p < 16; ++p)
        s[r + p * 4][c] = f2bf(Tmp[(size_t)(r0 + r + p * 4) * 64 + c]);
    __syncthreads();
    const int j = tid & 63, nq = tid >> 6;
#pragma unroll
    for (int p = 0; p < 16; ++p) {
        int n = nq + p * 4;
        Tt[(size_t)n * NN + r0 + j] = s[j][n];
    }
}

// ---------------------------------------------------------------------------
// gemm v2: P[s][8192][64] (fp32 partials) = A(fp32)[m-tile][k-slice] @ Bt(bf16)^T
// A row-major [8192][8192] fp32; Bt [64][8192] bf16. Block: 64 rows x 64 cols.
// 256 thr = 4 waves; wave w owns output rows w*16..w*16+15.
// Double-buffered LDS (2 x 8KB A, 2 x 8KB B = 32 KB); one barrier per K-step.
__global__ __launch_bounds__(256) void gemm_af32_bt(const float* __restrict__ A,
                                                    const u16* __restrict__ Bt,
                                                    float* __restrict__ P,
                                                    int kslice) {
    __shared__ __align__(16) u16 As[2][MT * BK];  // XOR-swizzled
    __shared__ __align__(16) u16 Bs[2][MT * BK];  // XOR-swizzled
    const int tid = threadIdx.x;
    const int w = tid >> 6;   // wave 0..3
    const int l = tid & 63;   // lane
    const int m0 = blockIdx.x * MT;
    const int s = blockIdx.y;
    const int k0 = s * kslice;

    f32x4 acc[4] = {f32x4{0,0,0,0}, f32x4{0,0,0,0}, f32x4{0,0,0,0}, f32x4{0,0,0,0}};

    // ---- A staging (manual fp32->bf16): thread t -> row t>>2, col chunk t&3
    // LDS convention: As[b][r][g'] = global A[r][g'^(r&7)]  (groups of 8 elems)
    const int ar = tid >> 2;          // 0..63
    const int ac = tid & 3;           // chunk of 16 cols
    const float* Ap = A + (size_t)(m0 + ar) * NN + (size_t)k0 + ac * 16;
    const int arow = ar * 64;
    const int g0 = (2 * ac) ^ (ar & 7);
    const int g1 = (2 * ac + 1) ^ (ar & 7);

    // ---- B staging via global_load_lds: wave w loads Bt rows w*16..w*16+15
    // (global source pre-swizzled so linear LDS dest lands swizzled -- m173)
    const int lr = l >> 3;
    const int lc = (l & 7) ^ lr;
    const u16* Bb = Bt + (size_t)(w * 16 + lr) * NN + lc * 8 + k0;
    const int bwoff = (w * 16) * 128;  // byte offset of this wave's rows in a B buffer

    // ---- fragment read indices
    const int fm = w * 16 + (l & 15);  // A frag row (this wave's rows)
    const int q = l >> 4;              // quad -> k subgroup

    const int nt = kslice / BK;

    // ---- prologue: stage tile 0 into buffer 0
    __builtin_amdgcn_global_load_lds(GAS(Bb), LAS((char*)Bs + bwoff), 16, 0, 0);
    __builtin_amdgcn_global_load_lds(GAS(Bb + 8 * NN), LAS((char*)Bs + bwoff + 1024), 16, 0, 0);
    {
        f32x4 f0 = *(const f32x4*)(Ap);
        f32x4 f1 = *(const f32x4*)(Ap + 4);
        f32x4 f2 = *(const f32x4*)(Ap + 8);
        f32x4 f3 = *(const f32x4*)(Ap + 12);
        uint4 p0{pk2(f0.x, f0.y), pk2(f0.z, f0.w), pk2(f1.x, f1.y), pk2(f1.z, f1.w)};
        uint4 p1{pk2(f2.x, f2.y), pk2(f2.z, f2.w), pk2(f3.x, f3.y), pk2(f3.z, f3.w)};
        *(uint4*)(&As[0][arow + g0 * 8]) = p0;
        *(uint4*)(&As[0][arow + g1 * 8]) = p1;
    }
    __syncthreads();  // drains vmcnt(0): tile 0 fully in LDS

    int cur = 0;
    for (int t = 0; t < nt; ++t) {
        const int nxt = cur ^ 1;
        const bool pre = (t + 1 < nt);
        f32x4 f0, f1, f2, f3;
        if (pre) {
            // issue next tile's loads FIRST -- latency hides under the MFMA phase
            const int kt = (t + 1) * BK;
            char* BsB = (char*)Bs + nxt * (MT * BK * 2) + bwoff;
            __builtin_amdgcn_global_load_lds(GAS(Bb + kt), LAS(BsB), 16, 0, 0);
            __builtin_amdgcn_global_load_lds(GAS(Bb + kt + 8 * NN), LAS(BsB + 1024), 16, 0, 0);
            f0 = *(const f32x4*)(Ap + kt);
            f1 = *(const f32x4*)(Ap + kt + 4);
            f2 = *(const f32x4*)(Ap + kt + 8);
            f3 = *(const f32x4*)(Ap + kt + 12);
        }
        // ---- MFMA phase on buffer `cur` (no global dependency)
        const u16* Asc = &As[cur][0];
        const u16* Bsc = &Bs[cur][0];
#pragma unroll
        for (int kk = 0; kk < 2; ++kk) {
            const int acg = (kk * 4 + q) ^ (fm & 7);
            s16x8 af = *(const s16x8*)&Asc[fm * 64 + acg * 8];
#pragma unroll
            for (int ng = 0; ng < 4; ++ng) {
                const int bn = ng * 16 + (l & 15);
                const int bc = (kk * 4 + q) ^ (bn & 7);
                s16x8 bf = *(const s16x8*)&Bsc[bn * 64 + bc * 8];
                acc[ng] = __builtin_amdgcn_mfma_f32_16x16x32_bf16(af, bf, acc[ng], 0, 0, 0);
            }
        }
        if (pre) {
            // convert + write A into the next buffer (vmcnt wait lands here,
            // ~a full compute phase after issue)
            uint4 p0{pk2(f0.x, f0.y), pk2(f0.z, f0.w), pk2(f1.x, f1.y), pk2(f1.z, f1.w)};
            uint4 p1{pk2(f2.x, f2.y), pk2(f2.z, f2.w), pk2(f3.x, f3.y), pk2(f3.z, f3.w)};
            *(uint4*)(&As[nxt][arow + g0 * 8]) = p0;
            *(uint4*)(&As[nxt][arow + g1 * 8]) = p1;
        }
        __syncthreads();  // one barrier/iter: drains B gload_lds + A ds_writes
        cur = nxt;
    }

    // epilogue: C/D map col=lane&15, row=(lane>>4)*4+reg  (m89-verified)
    float* Pp = P + (size_t)s * NN * 64;
    const int row = m0 + w * 16 + (l >> 4) * 4;
    const int col = l & 15;
#pragma unroll
    for (int ng = 0; ng < 4; ++ng)
#pragma unroll
        for (int r = 0; r < 4; ++r)
            Pp[(size_t)(row + r) * 64 + ng * 16 + col] = acc[ng][r];
}

// ---------------------------------------------------------------------------
// k4: St[n][j] = bf16( filt[j] * sum_s P[s][j][n] )   (reduce+scale+transpose)
__global__ __launch_bounds__(256) void k4_reduce_scale_t(const float* __restrict__ P,
                                                         const float* __restrict__ filt,
                                                         u16* __restrict__ St,
                                                         int split) {
    __shared__ u16 s[64][65];
    const int tid = threadIdx.x;
    const int j0 = blockIdx.x * 64;
    const int n = tid & 63, jq = tid >> 6;
#pragma unroll 4
    for (int p = 0; p < 16; ++p) {
        int j = jq + p * 4;
        float acc = 0.f;
        for (int t = 0; t < split; ++t)
            acc += P[((size_t)t * NN + j0 + j) * 64 + n];
        acc *= filt[j0 + j];
        s[j][n] = f2bf(acc);
    }
    __syncthreads();
    const int jj = tid & 63, nq = tid >> 6;
#pragma unroll
    for (int p = 0; p < 16; ++p) {
        int nn = nq + p * 4;
        St[(size_t)nn * NN + j0 + jj] = s[jj][nn];
    }
}

// ---------------------------------------------------------------------------
// k6: out[idx] = fp32( sum_s P[s][idx] )
__global__ __launch_bounds__(256) void k6_reduce_out(const float* __restrict__ P,
                                                     float* __restrict__ out,
                                                     int split) {
    const int idx = blockIdx.x * 256 + threadIdx.x;
    float acc = 0.f;
    for (int t = 0; t < split; ++t)
        acc += P[(size_t)t * NN * 64 + idx];
    out[idx] = acc;
}

// ---------------------------------------------------------------------------
extern "C" void kernel_launch(void* const* d_in, const int* in_sizes, int n_in,
                              void* d_out, int out_size, void* d_ws, size_t ws_size,
                              hipStream_t stream) {
    const float* F    = (const float*)d_in[0];  // features   [8192][128]
    const float* W    = (const float*)d_in[1];  // weight     [128][64]
    const float* filt = (const float*)d_in[2];  // filt       [8192]
    const float* Wav  = (const float*)d_in[3];  // wavelets   [8192][8192]
    const float* Winv = (const float*)d_in[4];  // wavelets_inv
    float* out = (float*)d_out;

    char* ws = (char*)d_ws;
    u16* Tt = (u16*)ws;                      // [64][8192] bf16, 1 MB
    u16* St = (u16*)(ws + (1u << 20));       // [64][8192] bf16, 1 MB
    float* Tmp = (float*)(ws + (2u << 20));  // [8192][64] fp32, 2 MB (overlaid w/ P)
    float* P   = (float*)(ws + (2u << 20));  // [split][8192][64] fp32

    // K-split: as many power-of-two slices as ws allows, max 8 (18 MB total)
    size_t per = (size_t)NN * 64 * 4;
    size_t avail = (ws_size > (2u << 20)) ? ws_size - (2u << 20) : per;
    int maxs = (int)(avail / per);
    if (maxs < 1) maxs = 1;
    int split = 1;
    while (split * 2 <= maxs && split < 8) split *= 2;
    int kslice = NN / split;

    // 1. Tmp = features @ W  (fp32)
    k1_feat<<<512, 256, 0, stream>>>(F, W, Tmp);
    // 2. Tt = bf16(Tmp)^T
    k2_transpose<<<128, 256, 0, stream>>>(Tmp, Tt);
    // 3. P = Winv @ Tt^T (fp32 partials over K-slices)
    gemm_af32_bt<<<dim3(128, split), 256, 0, stream>>>(Winv, Tt, P, kslice);
    // 4. St = bf16(filt * reduce(P))^T
    k4_reduce_scale_t<<<128, 256, 0, stream>>>(P, filt, St, split);
    // 5. P = Wav @ St^T
    gemm_af32_bt<<<dim3(128, split), 256, 0, stream>>>(Wav, St, P, kslice);
    // 6. out = reduce(P)  (fp32)
    k6_reduce_out<<<2048, 256, 0, stream>>>(P, out, split);
}